// Round 13
// baseline (479.775 us; speedup 1.0000x reference)
//
#include <hip/hip_runtime.h>
#include <hip/hip_fp16.h>

#define NN 100000
#define NE 3200000
#define NG 128
#define HID 64

#define BSH 9                       // nodes per bucket = 512
#define BNODES 512
#define NBK ((NN + BNODES - 1) / BNODES)   // 196
#define CCH 8192                    // edges staged per block in bscatter
#define CAP 18432                   // fixed slots per bucket (E[cnt]=16327, +16 sigma)

typedef __attribute__((ext_vector_type(2))) _Float16 half2v;
typedef __attribute__((ext_vector_type(4))) _Float16 half4v;

#if __has_builtin(__builtin_amdgcn_fdot2)
#define FDOT2(v, o, a) __builtin_amdgcn_fdot2((v), (o), (a), false)
#else
static __device__ inline float FDOT2(half2v v, half2v o, float a) {
    return a + (float)v.x * (float)o.x + (float)v.y * (float)o.y;
}
#endif

// ---------------- scatter packed (dstLocal<<17 | src) into padded buckets ---
// r8-proven direct scatter. Zero-based bcur (bucket base b*CAP added here) so
// bcur can be zeroed by the launch memset.
__global__ __launch_bounds__(512) void bscatter_kernel(const int* __restrict__ src,
                                                       const int* __restrict__ dst,
                                                       int* __restrict__ bcur,
                                                       unsigned* __restrict__ pairs,
                                                       int E) {
    __shared__ unsigned stage[CCH];      // 32 KB
    __shared__ unsigned char bb[CCH];    // 8 KB
    __shared__ int cnt[NBK];
    __shared__ int base[NBK];
    const int e0 = blockIdx.x * CCH;
    const int n  = min(CCH, E - e0);
    if (n <= 0) return;
    for (int i = threadIdx.x; i < NBK; i += 512) cnt[i] = 0;
    __syncthreads();
    for (int i = threadIdx.x; i < n; i += 512) {
        int s = src[e0 + i], d = dst[e0 + i];
        int b = d >> BSH;
        stage[i] = ((unsigned)(d & (BNODES - 1)) << 17) | (unsigned)s;
        bb[i] = (unsigned char)b;
        atomicAdd(&cnt[b], 1);
    }
    __syncthreads();
    for (int i = threadIdx.x; i < NBK; i += 512) {
        int c = cnt[i];
        base[i] = c ? (i * CAP + atomicAdd(&bcur[i], c)) : 0;
        cnt[i] = 0;                 // reuse as local cursor
    }
    __syncthreads();
    for (int i = threadIdx.x; i < n; i += 512) {
        int b = bb[i];
        int pos = base[b] + atomicAdd(&cnt[b], 1);
        if (pos < (b + 1) * CAP)    // overflow guard (never triggers at 16 sigma)
            pairs[pos] = stage[i];
    }
}

// ---------------- per-bucket CSR build + x16h prep, single HBM pass ---------
// One block per bucket: stage pairs (<=72KB) in LDS, hist+scan+scatter from
// LDS. 512 threads, one node per thread. Writes rowse=int2{start,end}, dis,
// csr_src, AND x16h = fp16(x*dis) (xprep fused — sn already in register).
__global__ __launch_bounds__(512) void csr_kernel(const unsigned* __restrict__ pairs,
                                                  const int* __restrict__ bcur,
                                                  const float* __restrict__ x,
                                                  int2* __restrict__ rowse,
                                                  int* __restrict__ csr_src,
                                                  float* __restrict__ dis,
                                                  __half* __restrict__ x16h,
                                                  int N) {
    __shared__ unsigned stage[CAP];     // 72 KB
    __shared__ int hist[BNODES];
    __shared__ int cur[BNODES];
    __shared__ int s[BNODES];
    const int b     = blockIdx.x;
    const int t     = threadIdx.x;
    const int node0 = b << BSH;
    const int nn    = min(BNODES, N - node0);
    const int p0    = b * CAP;
    const int cnt   = min(bcur[b], CAP);

    for (int i = t; i < cnt; i += 512) stage[i] = pairs[p0 + i];
    hist[t] = 0;
    __syncthreads();
    for (int i = t; i < cnt; i += 512)
        atomicAdd(&hist[stage[i] >> 17], 1);
    __syncthreads();

    int h = hist[t];
    s[t] = h;
    __syncthreads();
#pragma unroll
    for (int off = 1; off < BNODES; off <<= 1) {
        int u = (t >= off) ? s[t - off] : 0;
        __syncthreads();
        s[t] += u;
        __syncthreads();
    }
    int e0 = p0 + s[t] - h;             // exclusive scan -> global slot base
    float sn = rsqrtf((float)h + 1.0f);
    if (t < nn) {
        rowse[node0 + t] = make_int2(e0, e0 + h);
        dis[node0 + t]   = sn;
    }
    cur[t] = e0;
    __syncthreads();

    for (int i = t; i < cnt; i += 512) {
        unsigned p = stage[i];
        int pos = atomicAdd(&cur[p >> 17], 1);
        csr_src[pos] = (int)(p & 0x1FFFFu);
    }

    // fused xprep: x16h[node,:] = fp16(x[node,:]*sn), col 15 zero-padded
    if (t < nn) {
        const int node = node0 + t;
        const float* xp = x + (size_t)node * 15;
        __align__(16) __half xr[16];
#pragma unroll
        for (int j = 0; j < 15; ++j) xr[j] = __float2half(xp[j] * sn);
        xr[15] = __float2half(0.0f);
        float4* dst4 = reinterpret_cast<float4*>(x16h + (size_t)node * 16);
        dst4[0] = reinterpret_cast<const float4*>(xr)[0];
        dst4[1] = reinterpret_cast<const float4*>(xr)[1];
    }
}

// ---------------- gather16: aggx = P_hat*(x*dis)  (4 lanes x 8B per node) ---
__global__ __launch_bounds__(256) void gather16_kernel(const half4v* __restrict__ xh,
                                                       const int* __restrict__ csr_src,
                                                       const int2* __restrict__ rowse,
                                                       const float* __restrict__ dis,
                                                       float4* __restrict__ aggx, int N) {
    const int gid  = blockIdx.x * 256 + threadIdx.x;
    const int node = gid >> 2;
    if (node >= N) return;
    const int l  = threadIdx.x & 3;
    const int gb = threadIdx.x & 60;
    const int2 se = rowse[node];
    const int start = se.x, end = se.y;
    const half2v ONEX = {(_Float16)1.0f, (_Float16)0.0f};
    const half2v ONEY = {(_Float16)0.0f, (_Float16)1.0f};
    float a0 = 0.0f, a1 = 0.0f, a2 = 0.0f, a3 = 0.0f;
    for (int j0 = start; j0 < end; j0 += 4) {
        int j   = j0 + l;
        int s   = (j < end) ? csr_src[j] : 0;
        int cnt = min(4, end - j0);
#pragma unroll
        for (int k = 0; k < 4; ++k) {
            int sk = __shfl(s, gb + k);
            if (k < cnt) {
                half4v v = xh[sk * 4 + l];
                half2v p0 = __builtin_shufflevector(v, v, 0, 1);
                half2v p1 = __builtin_shufflevector(v, v, 2, 3);
                a0 = FDOT2(p0, ONEX, a0);
                a1 = FDOT2(p0, ONEY, a1);
                a2 = FDOT2(p1, ONEX, a2);
                a3 = FDOT2(p1, ONEY, a3);
            }
        }
    }
    half4v sv = xh[node * 4 + l];
    half2v s0 = __builtin_shufflevector(sv, sv, 0, 1);
    half2v s1 = __builtin_shufflevector(sv, sv, 2, 3);
    a0 += (float)s0.x; a1 += (float)s0.y;
    a2 += (float)s1.x; a3 += (float)s1.y;
    float sn = dis[node];
    aggx[(size_t)node * 4 + l] = make_float4(sn * a0, sn * a1, sn * a2, sn * a3);
}

// ---------------- gemm12: th2 = fp16( relu(aggx@W1 + b1) @ W2 * dis ) -------
// fuses gemm1 + first gemmB via LDS h buffer (no h1pre round trip)
__global__ __launch_bounds__(256) void gemm12_kernel(const float* __restrict__ in,
                                                     const float* __restrict__ w1,
                                                     const float* __restrict__ b1,
                                                     const float* __restrict__ w2,
                                                     const float* __restrict__ dis,
                                                     __half* __restrict__ th_out, int N) {
    __shared__ float w1_s[16 * 64];   // 4 KB
    __shared__ float in_s[64 * 17];   // 4.3 KB
    __shared__ float w2_s[64 * 64];   // 16 KB
    __shared__ float h_s[64 * 65];    // 16.6 KB
    const int tid  = threadIdx.x;
    const int row0 = blockIdx.x * 64;
    const int rows = min(64, N - row0);

    for (int i = tid; i < 16 * 64; i += 256) w1_s[i] = (i < 15 * 64) ? w1[i] : 0.0f;
    for (int i = tid; i < 64 * 64; i += 256) w2_s[i] = w2[i];
    for (int i = tid; i < rows * 16; i += 256) {
        int r = i >> 4, k = i & 15;
        in_s[r * 17 + k] = in[(size_t)(row0 + r) * 16 + k];
    }
    __syncthreads();

    const int r  = tid & 63;
    const int cg = tid >> 6;
    {
        float acc[16];
#pragma unroll
        for (int i = 0; i < 16; ++i) acc[i] = 0.0f;
#pragma unroll
        for (int k = 0; k < 16; ++k) {
            float a = in_s[r * 17 + k];
#pragma unroll
            for (int cc = 0; cc < 16; ++cc)
                acc[cc] += a * w1_s[k * 64 + cg * 16 + cc];
        }
#pragma unroll
        for (int cc = 0; cc < 16; ++cc)
            h_s[r * 65 + cg * 16 + cc] = fmaxf(acc[cc] + b1[cg * 16 + cc], 0.0f);
    }
    __syncthreads();
    {
        const float2* w2v = reinterpret_cast<const float2*>(w2_s);
        float2 acc2[8];
#pragma unroll
        for (int i = 0; i < 8; ++i) acc2[i] = make_float2(0.0f, 0.0f);
#pragma unroll
        for (int k = 0; k < 64; ++k) {
            float a = h_s[r * 65 + k];
            const float2* wk = w2v + k * 32 + cg * 8;
#pragma unroll
            for (int i = 0; i < 8; ++i) {
                float2 wv = wk[i];
                acc2[i].x += a * wv.x;
                acc2[i].y += a * wv.y;
            }
        }
        const int row = row0 + r;
        if (row < N) {
            float sd = dis[row];
            __align__(16) __half2 hh[8];
#pragma unroll
            for (int i = 0; i < 8; ++i)
                hh[i] = __floats2half2_rn(acc2[i].x * sd, acc2[i].y * sd);
            float4* tp = reinterpret_cast<float4*>(th_out + (size_t)row * HID + cg * 16);
            tp[0] = reinterpret_cast<float4*>(hh)[0];
            tp[1] = reinterpret_cast<float4*>(hh)[1];
        }
    }
}

// ---------------- fusedGG: gather + GEMM in one pass ------------------------
// th_out[node,:] = fp16( dis*( relu( dis*(sum th_in[src,:] + self) + bias ) @ W ) )
// 8 nodes/block (32 lanes/node). r13: BARRIER-FREE after W staging — the old
// post-gather __syncthreads coupled 4 waves (block time = max degree of 8
// nodes ~ mu+1.43sigma vs per-wave max-of-2 ~ mu+0.56sigma). GEMM now gets u
// via __shfl broadcast within the half-wave (lane hb+m holds u[2m],u[2m+1]);
// same op count as the old LDS r_s path, no r_s, no coupling barrier.
__global__ __launch_bounds__(256) void fusedGG_kernel(const half2v* __restrict__ th_in,
                                                      const int* __restrict__ csr_src,
                                                      const int2* __restrict__ rowse,
                                                      const float* __restrict__ dis,
                                                      const float* __restrict__ w,
                                                      const float* __restrict__ bias,
                                                      __half* __restrict__ th_out, int N) {
    __shared__ float w_s[64 * 64];    // 16 KB
    const int tid = threadIdx.x;
    {   // stage W (row-major 64x64 fp32)
        const float4* wsrc = reinterpret_cast<const float4*>(w);
        float4* wdst = reinterpret_cast<float4*>(w_s);
        for (int i = tid; i < 1024; i += 256) wdst[i] = wsrc[i];
    }
    __syncthreads();                  // only barrier: w_s ready, up front
    const int g    = tid >> 5;              // node slot 0..7
    const int node = blockIdx.x * 8 + g;
    const int l    = tid & 31;
    const int hb   = tid & 32;              // shfl base for this half-wave
    if (node >= N) return;
    const int2 se = rowse[node];
    const int start = se.x, end = se.y;
    const half2v* tl = th_in + l;
    const half2v ONEX = {(_Float16)1.0f, (_Float16)0.0f};
    const half2v ONEY = {(_Float16)0.0f, (_Float16)1.0f};
    float ax = 0.0f, ay = 0.0f;
    for (int j0 = start; j0 < end; j0 += 32) {
        int j   = j0 + l;
        int s   = (j < end) ? csr_src[j] : 0;
        int cnt = min(32, end - j0);
        int k = 0;
        for (; k + 16 <= cnt; k += 16) {
            int sk[16];
#pragma unroll
            for (int u = 0; u < 16; ++u) sk[u] = __shfl(s, hb + k + u);
            half2v v[16];
#pragma unroll
            for (int u = 0; u < 16; ++u) v[u] = tl[sk[u] * 32];
#pragma unroll
            for (int u = 0; u < 16; ++u) {
                ax = FDOT2(v[u], ONEX, ax);
                ay = FDOT2(v[u], ONEY, ay);
            }
        }
        for (; k + 4 <= cnt; k += 4) {
            int s0 = __shfl(s, hb + k);
            int s1 = __shfl(s, hb + k + 1);
            int s2 = __shfl(s, hb + k + 2);
            int s3 = __shfl(s, hb + k + 3);
            half2v v0 = tl[s0 * 32];
            half2v v1 = tl[s1 * 32];
            half2v v2 = tl[s2 * 32];
            half2v v3 = tl[s3 * 32];
            ax = FDOT2(v0, ONEX, ax); ay = FDOT2(v0, ONEY, ay);
            ax = FDOT2(v1, ONEX, ax); ay = FDOT2(v1, ONEY, ay);
            ax = FDOT2(v2, ONEX, ax); ay = FDOT2(v2, ONEY, ay);
            ax = FDOT2(v3, ONEX, ax); ay = FDOT2(v3, ONEY, ay);
        }
        for (; k < cnt; ++k) {
            half2v v = tl[__shfl(s, hb + k) * 32];
            ax += (float)v.x; ay += (float)v.y;
        }
    }
    half2v self = tl[node * 32];
    ax += (float)self.x; ay += (float)self.y;
    const float sn = dis[node];
    const float2 bv = reinterpret_cast<const float2*>(bias)[l];
    const float u0 = fmaxf(sn * ax + bv.x, 0.0f);   // u[2l]
    const float u1 = fmaxf(sn * ay + bv.y, 0.0f);   // u[2l+1]

    // GEMM: c[2l],c[2l+1] = sum_k u[k] * W[k][2l..2l+1]; u via half-wave shfl
    float c0 = 0.0f, c1 = 0.0f;
    const float2* wv = reinterpret_cast<const float2*>(w_s);
#pragma unroll 8
    for (int m = 0; m < 32; ++m) {
        float uk0 = __shfl(u0, hb + m);             // u[2m]
        float uk1 = __shfl(u1, hb + m);             // u[2m+1]
        float2 w0 = wv[(2 * m) * 32 + l];
        float2 w1 = wv[(2 * m + 1) * 32 + l];
        c0 += uk0 * w0.x + uk1 * w1.x;
        c1 += uk0 * w0.y + uk1 * w1.y;
    }
    const float sd = sn;
    reinterpret_cast<__half2*>(th_out)[(size_t)node * 32 + l] =
        __floats2half2_rn(c0 * sd, c1 * sd);
}

// ---------------- gatherh_pool: final gather + relu(+b4) + mean-pool sum ----
// r8-proven 32 nodes/block. batch sorted, min graph ~700 >> 32: 32
// consecutive nodes span <=2 graphs; 4 LDS slots + global overflow guard.
__global__ __launch_bounds__(256) void gatherh_pool_kernel(const half2v* __restrict__ th,
                                                           const int* __restrict__ csr_src,
                                                           const int2* __restrict__ rowse,
                                                           const float* __restrict__ dis,
                                                           const float* __restrict__ b4,
                                                           const int* __restrict__ batch,
                                                           float* __restrict__ sums,
                                                           float* __restrict__ cnts, int N) {
    __shared__ float lsum[4 * HID];     // 1 KB
    __shared__ float lcnt[4];
    const int tid      = threadIdx.x;
    const int nodebase = blockIdx.x * 32;
    if (nodebase >= N) return;
    const int last   = min(nodebase + 32, N) - 1;
    const int gfirst = batch[nodebase];
    const int glast  = batch[last];
    const int span   = glast - gfirst + 1;

    for (int i = tid; i < 4 * HID; i += 256) lsum[i] = 0.0f;
    if (tid < 4) lcnt[tid] = 0.0f;
    __syncthreads();

    const int g  = tid >> 5;             // node slot 0..7 within a pass
    const int l  = tid & 31;
    const int hb = tid & 32;
    const half2v* tl = th + l;
    const half2v ONEX = {(_Float16)1.0f, (_Float16)0.0f};
    const half2v ONEY = {(_Float16)0.0f, (_Float16)1.0f};
    const float2 bv = reinterpret_cast<const float2*>(b4)[l];

    for (int it = 0; it < 4; ++it) {
        const int node = nodebase + it * 8 + g;
        if (node < N) {
            const int2 se = rowse[node];
            const int start = se.x, end = se.y;
            float ax = 0.0f, ay = 0.0f;
            for (int j0 = start; j0 < end; j0 += 32) {
                int j   = j0 + l;
                int s   = (j < end) ? csr_src[j] : 0;
                int cnt = min(32, end - j0);
                int k = 0;
                for (; k + 16 <= cnt; k += 16) {
                    int sk[16];
#pragma unroll
                    for (int u = 0; u < 16; ++u) sk[u] = __shfl(s, hb + k + u);
                    half2v v[16];
#pragma unroll
                    for (int u = 0; u < 16; ++u) v[u] = tl[sk[u] * 32];
#pragma unroll
                    for (int u = 0; u < 16; ++u) {
                        ax = FDOT2(v[u], ONEX, ax);
                        ay = FDOT2(v[u], ONEY, ay);
                    }
                }
                for (; k + 4 <= cnt; k += 4) {
                    int s0 = __shfl(s, hb + k);
                    int s1 = __shfl(s, hb + k + 1);
                    int s2 = __shfl(s, hb + k + 2);
                    int s3 = __shfl(s, hb + k + 3);
                    half2v v0 = tl[s0 * 32];
                    half2v v1 = tl[s1 * 32];
                    half2v v2 = tl[s2 * 32];
                    half2v v3 = tl[s3 * 32];
                    ax = FDOT2(v0, ONEX, ax); ay = FDOT2(v0, ONEY, ay);
                    ax = FDOT2(v1, ONEX, ax); ay = FDOT2(v1, ONEY, ay);
                    ax = FDOT2(v2, ONEX, ax); ay = FDOT2(v2, ONEY, ay);
                    ax = FDOT2(v3, ONEX, ax); ay = FDOT2(v3, ONEY, ay);
                }
                for (; k < cnt; ++k) {
                    half2v v = tl[__shfl(s, hb + k) * 32];
                    ax += (float)v.x; ay += (float)v.y;
                }
            }
            half2v self = tl[node * 32];
            ax += (float)self.x; ay += (float)self.y;
            const float sn = dis[node];
            const float v0 = fmaxf(fmaf(sn, ax, bv.x), 0.0f);
            const float v1 = fmaxf(fmaf(sn, ay, bv.y), 0.0f);
            const int slot = batch[node] - gfirst;
            if (slot < 4) {
                atomicAdd(&lsum[slot * HID + 2 * l], v0);
                atomicAdd(&lsum[slot * HID + 2 * l + 1], v1);
                if (l == 0) atomicAdd(&lcnt[slot], 1.0f);
            } else {    // pathological tiny-graph overflow: straight to global
                atomicAdd(&sums[(size_t)(gfirst + slot) * HID + 2 * l], v0);
                atomicAdd(&sums[(size_t)(gfirst + slot) * HID + 2 * l + 1], v1);
                if (l == 0) atomicAdd(&cnts[gfirst + slot], 1.0f);
            }
        }
    }
    __syncthreads();

    const int flush = min(span, 4) * HID;
    for (int i = tid; i < flush; i += 256)
        if (lsum[i] != 0.0f) atomicAdd(&sums[(size_t)gfirst * HID + i], lsum[i]);
    if (tid < 4 && tid < span && lcnt[tid] != 0.0f)
        atomicAdd(&cnts[gfirst + tid], lcnt[tid]);
}

__global__ __launch_bounds__(256) void finalize_kernel(const float* __restrict__ sums,
                                                       const float* __restrict__ cnts,
                                                       float* __restrict__ out) {
    int i = blockIdx.x * 256 + threadIdx.x;
    if (i < NG * HID) out[i] = sums[i] / fmaxf(cnts[i >> 6], 1.0f);
}

// ---------------- launch ----------------
extern "C" void kernel_launch(void* const* d_in, const int* in_sizes, int n_in,
                              void* d_out, int out_size, void* d_ws, size_t ws_size,
                              hipStream_t stream) {
    const float* x  = (const float*)d_in[0];
    const float* w1 = (const float*)d_in[1];
    const float* b1 = (const float*)d_in[2];
    const float* w2 = (const float*)d_in[3];
    const float* b2 = (const float*)d_in[4];
    const float* w3 = (const float*)d_in[5];
    const float* b3 = (const float*)d_in[6];
    const float* w4 = (const float*)d_in[7];
    const float* b4 = (const float*)d_in[8];
    const int* ei    = (const int*)d_in[9];
    const int* batch = (const int*)d_in[10];
    const int* src = ei;
    const int* dst = ei + NE;

    // workspace layout (~59 MB):
    //   thB 12.8 | thA 12.8 | pairs_pad 14.5 (aggx 6.4 aliases it after csr) |
    //   csr_src_pad 14.5 | rowse 0.8 | dis 0.4 | bcur,sums,cnts (one
    //   contiguous memset) | x16h 3.2
    __half*   thB      = (__half*)d_ws;                          // 12.8 MB
    __half*   thA      = thB + (size_t)NN * HID;                 // 12.8 MB
    unsigned* pairs    = (unsigned*)(thA + (size_t)NN * HID);    // NBK*CAP*4 = 14.5 MB
    float*    aggx     = (float*)pairs;                          // 6.4 MB (alias, post-csr)
    int*      csr_src  = (int*)(pairs + (size_t)NBK * CAP);      // 14.5 MB
    int2*     rowse    = (int2*)(csr_src + (size_t)NBK * CAP);   // NN int2
    float*    dis      = (float*)(rowse + NN);                   // NN
    int*      bcur     = (int*)(dis + NN);                       // NBK (memset region start)
    float*    sums     = (float*)(bcur + NBK);                   // NG*HID (memset)
    float*    cnts     = sums + NG * HID;                        // NG (memset region end)
    __half*   x16h     = (__half*)(cnts + NG);                   // NN*16 = 3.2 MB

    float* out = (float*)d_out;

    const int GB  = (NN + 63) / 64;          // gemm12: 64 nodes/block
    const int OB  = (NN * 4 + 255) / 256;    // gather16: 4 lanes/node
    const int FB  = (NN + 7) / 8;            // fusedGG: 8 nodes/block
    const int PB  = (NN + 31) / 32;          // gatherh_pool: 32 nodes/block
    const int CB  = (NE + CCH - 1) / CCH;

    // zero bcur + sums + cnts in one shot
    hipMemsetAsync(bcur, 0, (NBK + NG * HID + NG) * sizeof(int), stream);

    bscatter_kernel<<<CB, 512, 0, stream>>>(src, dst, bcur, pairs, NE);
    csr_kernel<<<NBK, 512, 0, stream>>>(pairs, bcur, x, rowse, csr_src, dis, x16h, NN);

    // layer 1 (commuted) + layer-2 linear: th2 = f(P x)
    gather16_kernel<<<OB, 256, 0, stream>>>((const half4v*)x16h, csr_src, rowse,
                                            dis, (float4*)aggx, NN);
    gemm12_kernel<<<GB, 256, 0, stream>>>(aggx, w1, b1, w2, dis, thA, NN);
    // layers 2->3, 3->4 fused gather+GEMM (barrier-free)
    fusedGG_kernel<<<FB, 256, 0, stream>>>((const half2v*)thA, csr_src, rowse,
                                           dis, w3, b2, thB, NN);
    fusedGG_kernel<<<FB, 256, 0, stream>>>((const half2v*)thB, csr_src, rowse,
                                           dis, w4, b3, thA, NN);
    // final gather (layer 4 aggregation) fused with relu(+b4) + mean-pool sums
    gatherh_pool_kernel<<<PB, 256, 0, stream>>>((const half2v*)thA, csr_src, rowse,
                                                dis, b4, batch, sums, cnts, NN);

    finalize_kernel<<<(NG * HID + 255) / 256, 256, 0, stream>>>(sums, cnts, out);
}

// Round 14
// 441.127 us; speedup vs baseline: 1.0876x; 1.0876x over previous
//
#include <hip/hip_runtime.h>
#include <hip/hip_fp16.h>

#define NN 100000
#define NE 3200000
#define NG 128
#define HID 64

#define BSH 9                       // nodes per bucket = 512
#define BNODES 512
#define NBK ((NN + BNODES - 1) / BNODES)   // 196
#define CCH 8192                    // edges staged per block in bscatter
#define CAP 18432                   // fixed slots per bucket (E[cnt]=16327, +16 sigma)

typedef __attribute__((ext_vector_type(2))) _Float16 half2v;
typedef __attribute__((ext_vector_type(4))) _Float16 half4v;

#if __has_builtin(__builtin_amdgcn_fdot2)
#define FDOT2(v, o, a) __builtin_amdgcn_fdot2((v), (o), (a), false)
#else
static __device__ inline float FDOT2(half2v v, half2v o, float a) {
    return a + (float)v.x * (float)o.x + (float)v.y * (float)o.y;
}
#endif

// ---------------- bcur init: bucket write cursors at fixed bases ------------
__global__ __launch_bounds__(256) void binit_kernel(int* __restrict__ bcur) {
    int t = threadIdx.x;
    if (t < NBK) bcur[t] = t * CAP;
}

// ---------------- scatter packed (dstLocal<<17 | src) into padded buckets ---
// r8-proven direct scatter, 512 threads.
__global__ __launch_bounds__(512) void bscatter_kernel(const int* __restrict__ src,
                                                       const int* __restrict__ dst,
                                                       int* __restrict__ bcur,
                                                       unsigned* __restrict__ pairs,
                                                       int E) {
    __shared__ unsigned stage[CCH];      // 32 KB
    __shared__ unsigned char bb[CCH];    // 8 KB
    __shared__ int cnt[NBK];
    __shared__ int base[NBK];
    const int e0 = blockIdx.x * CCH;
    const int n  = min(CCH, E - e0);
    if (n <= 0) return;
    for (int i = threadIdx.x; i < NBK; i += 512) cnt[i] = 0;
    __syncthreads();
    for (int i = threadIdx.x; i < n; i += 512) {
        int s = src[e0 + i], d = dst[e0 + i];
        int b = d >> BSH;
        stage[i] = ((unsigned)(d & (BNODES - 1)) << 17) | (unsigned)s;
        bb[i] = (unsigned char)b;
        atomicAdd(&cnt[b], 1);
    }
    __syncthreads();
    for (int i = threadIdx.x; i < NBK; i += 512) {
        int c = cnt[i];
        base[i] = c ? atomicAdd(&bcur[i], c) : 0;
        cnt[i] = 0;                 // reuse as local cursor
    }
    __syncthreads();
    for (int i = threadIdx.x; i < n; i += 512) {
        int b = bb[i];
        int pos = base[b] + atomicAdd(&cnt[b], 1);
        if (pos < (b + 1) * CAP)    // overflow guard (never triggers at 16 sigma)
            pairs[pos] = stage[i];
    }
}

// ---------------- per-bucket CSR build, single HBM pass ---------------------
// One block per bucket: stage pairs (<=72KB) in LDS, hist+scan+scatter from
// LDS. 512 threads, one node per thread. Writes rowse=int2{start,end}.
__global__ __launch_bounds__(512) void csr_kernel(const unsigned* __restrict__ pairs,
                                                  const int* __restrict__ bcur,
                                                  int2* __restrict__ rowse,
                                                  int* __restrict__ csr_src,
                                                  float* __restrict__ dis,
                                                  int N) {
    __shared__ unsigned stage[CAP];     // 72 KB
    __shared__ int hist[BNODES];
    __shared__ int cur[BNODES];
    __shared__ int s[BNODES];
    const int b     = blockIdx.x;
    const int t     = threadIdx.x;
    const int node0 = b << BSH;
    const int nn    = min(BNODES, N - node0);
    const int p0    = b * CAP;
    const int cnt   = min(bcur[b] - p0, CAP);

    for (int i = t; i < cnt; i += 512) stage[i] = pairs[p0 + i];
    hist[t] = 0;
    __syncthreads();
    for (int i = t; i < cnt; i += 512)
        atomicAdd(&hist[stage[i] >> 17], 1);
    __syncthreads();

    int h = hist[t];
    s[t] = h;
    __syncthreads();
#pragma unroll
    for (int off = 1; off < BNODES; off <<= 1) {
        int u = (t >= off) ? s[t - off] : 0;
        __syncthreads();
        s[t] += u;
        __syncthreads();
    }
    int e0 = p0 + s[t] - h;             // exclusive scan -> global slot base
    if (t < nn) {
        rowse[node0 + t] = make_int2(e0, e0 + h);
        dis[node0 + t]   = rsqrtf((float)h + 1.0f);
    }
    cur[t] = e0;
    __syncthreads();

    for (int i = t; i < cnt; i += 512) {
        unsigned p = stage[i];
        int pos = atomicAdd(&cur[p >> 17], 1);
        csr_src[pos] = (int)(p & 0x1FFFFu);
    }
}

// ---------------- x16h prep: fp16( x[i,k]*dis[i] ), 0 pad -------------------
__global__ __launch_bounds__(256) void xprep_kernel(const float* __restrict__ x,
                                                    const float* __restrict__ dis,
                                                    __half* __restrict__ x16h, int N) {
    int gid = blockIdx.x * 256 + threadIdx.x;
    if (gid >= N * 16) return;
    int node = gid >> 4, k = gid & 15;
    float v = (k < 15) ? x[node * 15 + k] * dis[node] : 0.0f;
    x16h[gid] = __float2half(v);
}

// ---------------- gather16: aggx = P_hat*(x*dis)  (4 lanes x 8B per node) ---
__global__ __launch_bounds__(256) void gather16_kernel(const half4v* __restrict__ xh,
                                                       const int* __restrict__ csr_src,
                                                       const int2* __restrict__ rowse,
                                                       const float* __restrict__ dis,
                                                       float4* __restrict__ aggx, int N) {
    const int gid  = blockIdx.x * 256 + threadIdx.x;
    const int node = gid >> 2;
    if (node >= N) return;
    const int l  = threadIdx.x & 3;
    const int gb = threadIdx.x & 60;
    const int2 se = rowse[node];
    const int start = se.x, end = se.y;
    const half2v ONEX = {(_Float16)1.0f, (_Float16)0.0f};
    const half2v ONEY = {(_Float16)0.0f, (_Float16)1.0f};
    float a0 = 0.0f, a1 = 0.0f, a2 = 0.0f, a3 = 0.0f;
    for (int j0 = start; j0 < end; j0 += 4) {
        int j   = j0 + l;
        int s   = (j < end) ? csr_src[j] : 0;
        int cnt = min(4, end - j0);
#pragma unroll
        for (int k = 0; k < 4; ++k) {
            int sk = __shfl(s, gb + k);
            if (k < cnt) {
                half4v v = xh[sk * 4 + l];
                half2v p0 = __builtin_shufflevector(v, v, 0, 1);
                half2v p1 = __builtin_shufflevector(v, v, 2, 3);
                a0 = FDOT2(p0, ONEX, a0);
                a1 = FDOT2(p0, ONEY, a1);
                a2 = FDOT2(p1, ONEX, a2);
                a3 = FDOT2(p1, ONEY, a3);
            }
        }
    }
    half4v sv = xh[node * 4 + l];
    half2v s0 = __builtin_shufflevector(sv, sv, 0, 1);
    half2v s1 = __builtin_shufflevector(sv, sv, 2, 3);
    a0 += (float)s0.x; a1 += (float)s0.y;
    a2 += (float)s1.x; a3 += (float)s1.y;
    float sn = dis[node];
    aggx[(size_t)node * 4 + l] = make_float4(sn * a0, sn * a1, sn * a2, sn * a3);
}

// ---------------- gemm12: th2 = fp16( relu(aggx@W1 + b1) @ W2 * dis ) -------
// fuses gemm1 + first gemmB via LDS h buffer (no h1pre round trip)
__global__ __launch_bounds__(256) void gemm12_kernel(const float* __restrict__ in,
                                                     const float* __restrict__ w1,
                                                     const float* __restrict__ b1,
                                                     const float* __restrict__ w2,
                                                     const float* __restrict__ dis,
                                                     __half* __restrict__ th_out, int N) {
    __shared__ float w1_s[16 * 64];   // 4 KB
    __shared__ float in_s[64 * 17];   // 4.3 KB
    __shared__ float w2_s[64 * 64];   // 16 KB
    __shared__ float h_s[64 * 65];    // 16.6 KB
    const int tid  = threadIdx.x;
    const int row0 = blockIdx.x * 64;
    const int rows = min(64, N - row0);

    for (int i = tid; i < 16 * 64; i += 256) w1_s[i] = (i < 15 * 64) ? w1[i] : 0.0f;
    for (int i = tid; i < 64 * 64; i += 256) w2_s[i] = w2[i];
    for (int i = tid; i < rows * 16; i += 256) {
        int r = i >> 4, k = i & 15;
        in_s[r * 17 + k] = in[(size_t)(row0 + r) * 16 + k];
    }
    __syncthreads();

    const int r  = tid & 63;
    const int cg = tid >> 6;
    {
        float acc[16];
#pragma unroll
        for (int i = 0; i < 16; ++i) acc[i] = 0.0f;
#pragma unroll
        for (int k = 0; k < 16; ++k) {
            float a = in_s[r * 17 + k];
#pragma unroll
            for (int cc = 0; cc < 16; ++cc)
                acc[cc] += a * w1_s[k * 64 + cg * 16 + cc];
        }
#pragma unroll
        for (int cc = 0; cc < 16; ++cc)
            h_s[r * 65 + cg * 16 + cc] = fmaxf(acc[cc] + b1[cg * 16 + cc], 0.0f);
    }
    __syncthreads();
    {
        const float2* w2v = reinterpret_cast<const float2*>(w2_s);
        float2 acc2[8];
#pragma unroll
        for (int i = 0; i < 8; ++i) acc2[i] = make_float2(0.0f, 0.0f);
#pragma unroll
        for (int k = 0; k < 64; ++k) {
            float a = h_s[r * 65 + k];
            const float2* wk = w2v + k * 32 + cg * 8;
#pragma unroll
            for (int i = 0; i < 8; ++i) {
                float2 wv = wk[i];
                acc2[i].x += a * wv.x;
                acc2[i].y += a * wv.y;
            }
        }
        const int row = row0 + r;
        if (row < N) {
            float sd = dis[row];
            __align__(16) __half2 hh[8];
#pragma unroll
            for (int i = 0; i < 8; ++i)
                hh[i] = __floats2half2_rn(acc2[i].x * sd, acc2[i].y * sd);
            float4* tp = reinterpret_cast<float4*>(th_out + (size_t)row * HID + cg * 16);
            tp[0] = reinterpret_cast<float4*>(hh)[0];
            tp[1] = reinterpret_cast<float4*>(hh)[1];
        }
    }
}

// ---------------- fusedGG: gather + GEMM in one pass ------------------------
// th_out[node,:] = fp16( dis*( relu( dis*(sum th_in[src,:] + self) + bias ) @ W ) )
// 8 nodes/block (32 lanes/node); row handoff via LDS r_s (broadcast reads are
// free — r13's shfl-GEMM variant cost +23us: ds_bpermute on the LDS pipe).
// Round 0-4 lesson: this 32-lane/half2 core (32 VGPR, ~76% occ) beats every
// wider-load variant (8/16-lane half8/half4 all land at 72-76 VGPR -> 4
// waves/SIMD -> latency-exposed; pinning spills). r13 lesson: the post-gather
// barrier costs ~0 (inter-block overlap hides intra-block imbalance).
__global__ __launch_bounds__(256) void fusedGG_kernel(const half2v* __restrict__ th_in,
                                                      const int* __restrict__ csr_src,
                                                      const int2* __restrict__ rowse,
                                                      const float* __restrict__ dis,
                                                      const float* __restrict__ w,
                                                      const float* __restrict__ bias,
                                                      __half* __restrict__ th_out, int N) {
    __shared__ float w_s[64 * 64];    // 16 KB
    __shared__ float r_s[8][64];      // 2 KB
    const int tid = threadIdx.x;
    {   // stage W (row-major 64x64 fp32)
        const float4* wsrc = reinterpret_cast<const float4*>(w);
        float4* wdst = reinterpret_cast<float4*>(w_s);
        for (int i = tid; i < 1024; i += 256) wdst[i] = wsrc[i];
    }
    const int g    = tid >> 5;              // node slot 0..7
    const int node = blockIdx.x * 8 + g;
    const int l    = tid & 31;
    const int hb   = tid & 32;              // shfl base for this half-wave
    float u0 = 0.0f, u1 = 0.0f;
    if (node < N) {
        const int2 se = rowse[node];
        const int start = se.x, end = se.y;
        const half2v* tl = th_in + l;
        const half2v ONEX = {(_Float16)1.0f, (_Float16)0.0f};
        const half2v ONEY = {(_Float16)0.0f, (_Float16)1.0f};
        float ax = 0.0f, ay = 0.0f;
        for (int j0 = start; j0 < end; j0 += 32) {
            int j   = j0 + l;
            int s   = (j < end) ? csr_src[j] : 0;
            int cnt = min(32, end - j0);
            int k = 0;
            for (; k + 16 <= cnt; k += 16) {
                int sk[16];
#pragma unroll
                for (int u = 0; u < 16; ++u) sk[u] = __shfl(s, hb + k + u);
                half2v v[16];
#pragma unroll
                for (int u = 0; u < 16; ++u) v[u] = tl[sk[u] * 32];
#pragma unroll
                for (int u = 0; u < 16; ++u) {
                    ax = FDOT2(v[u], ONEX, ax);
                    ay = FDOT2(v[u], ONEY, ay);
                }
            }
            for (; k + 4 <= cnt; k += 4) {
                int s0 = __shfl(s, hb + k);
                int s1 = __shfl(s, hb + k + 1);
                int s2 = __shfl(s, hb + k + 2);
                int s3 = __shfl(s, hb + k + 3);
                half2v v0 = tl[s0 * 32];
                half2v v1 = tl[s1 * 32];
                half2v v2 = tl[s2 * 32];
                half2v v3 = tl[s3 * 32];
                ax = FDOT2(v0, ONEX, ax); ay = FDOT2(v0, ONEY, ay);
                ax = FDOT2(v1, ONEX, ax); ay = FDOT2(v1, ONEY, ay);
                ax = FDOT2(v2, ONEX, ax); ay = FDOT2(v2, ONEY, ay);
                ax = FDOT2(v3, ONEX, ax); ay = FDOT2(v3, ONEY, ay);
            }
            for (; k < cnt; ++k) {
                half2v v = tl[__shfl(s, hb + k) * 32];
                ax += (float)v.x; ay += (float)v.y;
            }
        }
        half2v self = tl[node * 32];
        ax += (float)self.x; ay += (float)self.y;
        float sn = dis[node];
        float2 bv = reinterpret_cast<const float2*>(bias)[l];
        u0 = fmaxf(sn * ax + bv.x, 0.0f);
        u1 = fmaxf(sn * ay + bv.y, 0.0f);
    }
    reinterpret_cast<float2*>(r_s[g])[l] = make_float2(u0, u1);
    __syncthreads();
    if (node < N) {
        const float2* wv = reinterpret_cast<const float2*>(w_s);
        float c0 = 0.0f, c1 = 0.0f;
#pragma unroll 8
        for (int k = 0; k < 64; ++k) {
            float u = r_s[g][k];
            float2 ww = wv[k * 32 + l];
            c0 += u * ww.x;
            c1 += u * ww.y;
        }
        float sd = dis[node];
        reinterpret_cast<__half2*>(th_out)[(size_t)node * 32 + l] =
            __floats2half2_rn(c0 * sd, c1 * sd);
    }
}

// ---------------- gatherh_pool: final gather + relu(+b4) + mean-pool sum ----
// r8-proven 32 nodes/block. batch sorted, min graph ~700 >> 32: 32
// consecutive nodes span <=2 graphs; 4 LDS slots + global overflow guard.
__global__ __launch_bounds__(256) void gatherh_pool_kernel(const half2v* __restrict__ th,
                                                           const int* __restrict__ csr_src,
                                                           const int2* __restrict__ rowse,
                                                           const float* __restrict__ dis,
                                                           const float* __restrict__ b4,
                                                           const int* __restrict__ batch,
                                                           float* __restrict__ sums,
                                                           float* __restrict__ cnts, int N) {
    __shared__ float lsum[4 * HID];     // 1 KB
    __shared__ float lcnt[4];
    const int tid      = threadIdx.x;
    const int nodebase = blockIdx.x * 32;
    if (nodebase >= N) return;
    const int last   = min(nodebase + 32, N) - 1;
    const int gfirst = batch[nodebase];
    const int glast  = batch[last];
    const int span   = glast - gfirst + 1;

    for (int i = tid; i < 4 * HID; i += 256) lsum[i] = 0.0f;
    if (tid < 4) lcnt[tid] = 0.0f;
    __syncthreads();

    const int g  = tid >> 5;             // node slot 0..7 within a pass
    const int l  = tid & 31;
    const int hb = tid & 32;
    const half2v* tl = th + l;
    const half2v ONEX = {(_Float16)1.0f, (_Float16)0.0f};
    const half2v ONEY = {(_Float16)0.0f, (_Float16)1.0f};
    const float2 bv = reinterpret_cast<const float2*>(b4)[l];

    for (int it = 0; it < 4; ++it) {
        const int node = nodebase + it * 8 + g;
        if (node < N) {
            const int2 se = rowse[node];
            const int start = se.x, end = se.y;
            float ax = 0.0f, ay = 0.0f;
            for (int j0 = start; j0 < end; j0 += 32) {
                int j   = j0 + l;
                int s   = (j < end) ? csr_src[j] : 0;
                int cnt = min(32, end - j0);
                int k = 0;
                for (; k + 16 <= cnt; k += 16) {
                    int sk[16];
#pragma unroll
                    for (int u = 0; u < 16; ++u) sk[u] = __shfl(s, hb + k + u);
                    half2v v[16];
#pragma unroll
                    for (int u = 0; u < 16; ++u) v[u] = tl[sk[u] * 32];
#pragma unroll
                    for (int u = 0; u < 16; ++u) {
                        ax = FDOT2(v[u], ONEX, ax);
                        ay = FDOT2(v[u], ONEY, ay);
                    }
                }
                for (; k + 4 <= cnt; k += 4) {
                    int s0 = __shfl(s, hb + k);
                    int s1 = __shfl(s, hb + k + 1);
                    int s2 = __shfl(s, hb + k + 2);
                    int s3 = __shfl(s, hb + k + 3);
                    half2v v0 = tl[s0 * 32];
                    half2v v1 = tl[s1 * 32];
                    half2v v2 = tl[s2 * 32];
                    half2v v3 = tl[s3 * 32];
                    ax = FDOT2(v0, ONEX, ax); ay = FDOT2(v0, ONEY, ay);
                    ax = FDOT2(v1, ONEX, ax); ay = FDOT2(v1, ONEY, ay);
                    ax = FDOT2(v2, ONEX, ax); ay = FDOT2(v2, ONEY, ay);
                    ax = FDOT2(v3, ONEX, ax); ay = FDOT2(v3, ONEY, ay);
                }
                for (; k < cnt; ++k) {
                    half2v v = tl[__shfl(s, hb + k) * 32];
                    ax += (float)v.x; ay += (float)v.y;
                }
            }
            half2v self = tl[node * 32];
            ax += (float)self.x; ay += (float)self.y;
            const float sn = dis[node];
            const float v0 = fmaxf(fmaf(sn, ax, bv.x), 0.0f);
            const float v1 = fmaxf(fmaf(sn, ay, bv.y), 0.0f);
            const int slot = batch[node] - gfirst;
            if (slot < 4) {
                atomicAdd(&lsum[slot * HID + 2 * l], v0);
                atomicAdd(&lsum[slot * HID + 2 * l + 1], v1);
                if (l == 0) atomicAdd(&lcnt[slot], 1.0f);
            } else {    // pathological tiny-graph overflow: straight to global
                atomicAdd(&sums[(size_t)(gfirst + slot) * HID + 2 * l], v0);
                atomicAdd(&sums[(size_t)(gfirst + slot) * HID + 2 * l + 1], v1);
                if (l == 0) atomicAdd(&cnts[gfirst + slot], 1.0f);
            }
        }
    }
    __syncthreads();

    const int flush = min(span, 4) * HID;
    for (int i = tid; i < flush; i += 256)
        if (lsum[i] != 0.0f) atomicAdd(&sums[(size_t)gfirst * HID + i], lsum[i]);
    if (tid < 4 && tid < span && lcnt[tid] != 0.0f)
        atomicAdd(&cnts[gfirst + tid], lcnt[tid]);
}

__global__ __launch_bounds__(256) void finalize_kernel(const float* __restrict__ sums,
                                                       const float* __restrict__ cnts,
                                                       float* __restrict__ out) {
    int i = blockIdx.x * 256 + threadIdx.x;
    if (i < NG * HID) out[i] = sums[i] / fmaxf(cnts[i >> 6], 1.0f);
}

// ---------------- launch ----------------
extern "C" void kernel_launch(void* const* d_in, const int* in_sizes, int n_in,
                              void* d_out, int out_size, void* d_ws, size_t ws_size,
                              hipStream_t stream) {
    const float* x  = (const float*)d_in[0];
    const float* w1 = (const float*)d_in[1];
    const float* b1 = (const float*)d_in[2];
    const float* w2 = (const float*)d_in[3];
    const float* b2 = (const float*)d_in[4];
    const float* w3 = (const float*)d_in[5];
    const float* b3 = (const float*)d_in[6];
    const float* w4 = (const float*)d_in[7];
    const float* b4 = (const float*)d_in[8];
    const int* ei    = (const int*)d_in[9];
    const int* batch = (const int*)d_in[10];
    const int* src = ei;
    const int* dst = ei + NE;

    // workspace layout (~56 MB):
    //   thB 12.8 | thA 12.8 | pairs_pad 14.5 (overlaid by x16h 3.2 + aggx 6.4
    //   after csr) | csr_src_pad 14.5 | rowse/dis/bcur/sums/cnts
    __half*   thB      = (__half*)d_ws;                          // 12.8 MB
    __half*   thA      = thB + (size_t)NN * HID;                 // 12.8 MB
    unsigned* pairs    = (unsigned*)(thA + (size_t)NN * HID);    // NBK*CAP*4 = 14.5 MB
    __half*   x16h     = (__half*)pairs;                         // 3.2 MB (alias)
    float*    aggx     = (float*)(x16h + (size_t)NN * 16);       // 6.4 MB (alias)
    int*      csr_src  = (int*)(pairs + (size_t)NBK * CAP);      // 14.5 MB
    int2*     rowse    = (int2*)(csr_src + (size_t)NBK * CAP);   // NN int2
    float*    dis      = (float*)(rowse + NN);                   // NN
    int*      bcur     = (int*)(dis + NN);                       // NBK
    float*    sums     = (float*)(bcur + NBK);                   // NG*HID
    float*    cnts     = sums + NG * HID;                        // NG

    float* out = (float*)d_out;

    const int GB  = (NN + 63) / 64;          // gemm12: 64 nodes/block
    const int XB  = (NN * 16 + 255) / 256;   // xprep
    const int OB  = (NN * 4 + 255) / 256;    // gather16: 4 lanes/node
    const int FB  = (NN + 7) / 8;            // fusedGG: 8 nodes/block
    const int PB  = (NN + 31) / 32;          // gatherh_pool: 32 nodes/block
    const int CB  = (NE + CCH - 1) / CCH;

    hipMemsetAsync(sums, 0, (NG * HID + NG) * sizeof(float), stream);

    binit_kernel<<<1, 256, 0, stream>>>(bcur);
    bscatter_kernel<<<CB, 512, 0, stream>>>(src, dst, bcur, pairs, NE);
    csr_kernel<<<NBK, 512, 0, stream>>>(pairs, bcur, rowse, csr_src, dis, NN);

    // layer 1 (commuted) + layer-2 linear, fused: th2 = f(P x)
    xprep_kernel<<<XB, 256, 0, stream>>>(x, dis, x16h, NN);
    gather16_kernel<<<OB, 256, 0, stream>>>((const half4v*)x16h, csr_src, rowse,
                                            dis, (float4*)aggx, NN);
    gemm12_kernel<<<GB, 256, 0, stream>>>(aggx, w1, b1, w2, dis, thA, NN);
    // layers 2->3, 3->4 fused gather+GEMM
    fusedGG_kernel<<<FB, 256, 0, stream>>>((const half2v*)thA, csr_src, rowse,
                                           dis, w3, b2, thB, NN);
    fusedGG_kernel<<<FB, 256, 0, stream>>>((const half2v*)thB, csr_src, rowse,
                                           dis, w4, b3, thA, NN);
    // final gather (layer 4 aggregation) fused with relu(+b4) + mean-pool sums
    gatherh_pool_kernel<<<PB, 256, 0, stream>>>((const half2v*)thA, csr_src, rowse,
                                                dis, b4, batch, sums, cnts, NN);

    finalize_kernel<<<(NG * HID + 255) / 256, 256, 0, stream>>>(sums, cnts, out);
}